// Round 6
// baseline (299.466 us; speedup 1.0000x reference)
//
#include <hip/hip_runtime.h>
#include <stdint.h>

// Problem constants
#define TT     48000   // T
#define TK     120     // samples per chunk (T/K)
#define NC     128     // CIN == COUT
#define NA     384     // CIN*KS
#define NZ     64
#define NH     32
#define NK     400
#define NCHUNK 1600    // B*K
#define MW     49152   // CIN*COUT*KS
#define XROWS  48002   // T + 2 zero prefix rows (causal taps)

typedef float f32x4 __attribute__((ext_vector_type(4)));
typedef __bf16 bf16x8 __attribute__((ext_vector_type(8)));

static __device__ __forceinline__ uint16_t f2bf(float f) {
    uint32_t x; __builtin_memcpy(&x, &f, 4);
    return (uint16_t)((x + 0x7fffu + ((x >> 16) & 1u)) >> 16);
}

// ---------------------------------------------------------------------------
// k0x: transpose x[b][cin][t] f32 -> Xt[b][t+2][cin] bf16 (2 zero prefix rows)
// tile: 128 t x 64 cin per block
// ---------------------------------------------------------------------------
__global__ __launch_bounds__(256) void k0x(
    const float* __restrict__ x, uint16_t* __restrict__ Xt) {
    int t0 = blockIdx.x * 128, cin0 = blockIdx.y * 64, b = blockIdx.z;
    int tid = threadIdx.x;
    __shared__ __align__(16) uint16_t Lt[128][72];   // pad row to 72 (144B)
    const float* xb = x + ((size_t)b * NC + cin0) * TT + t0;
    int cg = (tid & 7) * 8;    // local cin base (0..56)
    int tq = (tid >> 3) * 4;   // local t base   (0..124)
    uint16_t vb[4][8];         // [t][cin]
#pragma unroll
    for (int i = 0; i < 8; ++i) {
        float4 v = *(const float4*)(xb + (size_t)(cg + i) * TT + tq);
        vb[0][i] = f2bf(v.x); vb[1][i] = f2bf(v.y);
        vb[2][i] = f2bf(v.z); vb[3][i] = f2bf(v.w);
    }
#pragma unroll
    for (int j = 0; j < 4; ++j) {
        uint4 o; __builtin_memcpy(&o, vb[j], 16);
        *(uint4*)&Lt[tq + j][cg] = o;
    }
    __syncthreads();
    uint16_t* XtB = Xt + (size_t)b * XROWS * NC;
#pragma unroll
    for (int r = 0; r < 4; ++r) {
        int s = r * 256 + tid;
        int t = s >> 3, cc = s & 7;
        uint4 o = *(uint4*)&Lt[t][cc * 8];
        *(uint4*)(XtB + (size_t)(t0 + t + 2) * NC + cin0 + cc * 8) = o;
    }
    if (blockIdx.x == 0 && blockIdx.y == 0 && tid < 32)
        *(uint4*)(XtB + tid * 8) = make_uint4(0, 0, 0, 0);  // zero rows -2,-1
}

// ---------------------------------------------------------------------------
// k1: 4 chunks per block (one per wave). All weights staged in LDS with
// conflict-free layouts; coalesced global loads.
// ---------------------------------------------------------------------------
__global__ __launch_bounds__(256) void k1_hidden(
    const float* __restrict__ z,
    const float* __restrict__ w1, const float* __restrict__ b1,
    const float* __restrict__ bw1, const float* __restrict__ bb1,
    const float* __restrict__ bw2, const float* __restrict__ bb2,
    uint16_t* __restrict__ Hb, float* __restrict__ biasws) {
    int tid = threadIdx.x, lane = tid & 63, w = tid >> 6;
    int chunk0 = blockIdx.x * 4;
    int b = chunk0 / NK;            // 400 % 4 == 0: all 4 chunks same b
    int k0 = chunk0 - b * NK;

    __shared__ float w1sT[64][33];   // [i][h] transposed, conflict-free reads
    __shared__ float bw1sT[64][33];
    __shared__ float bw2s[128][33];  // [c][j]
    __shared__ float zs[64][4];
    __shared__ float hbs[4][33];
    __shared__ float b1s[32], bb1s[32], bb2s[128];

    {   // stage w1, bw1 (transposed)
        int row = tid >> 3, c0 = (tid & 7) * 8;
        float4 a0 = *(const float4*)(w1 + row * NZ + c0);
        float4 a1 = *(const float4*)(w1 + row * NZ + c0 + 4);
        float4 c0v = *(const float4*)(bw1 + row * NZ + c0);
        float4 c1v = *(const float4*)(bw1 + row * NZ + c0 + 4);
        const float av[8] = {a0.x,a0.y,a0.z,a0.w,a1.x,a1.y,a1.z,a1.w};
        const float cv[8] = {c0v.x,c0v.y,c0v.z,c0v.w,c1v.x,c1v.y,c1v.z,c1v.w};
#pragma unroll
        for (int j = 0; j < 8; ++j) {
            w1sT[c0 + j][row]  = av[j];
            bw1sT[c0 + j][row] = cv[j];
        }
    }
    {   // stage bw2 [128][32]
        int r = tid >> 1, cb = (tid & 1) * 16;
        float4 v0 = *(const float4*)(bw2 + r * NH + cb);
        float4 v1 = *(const float4*)(bw2 + r * NH + cb + 4);
        float4 v2 = *(const float4*)(bw2 + r * NH + cb + 8);
        float4 v3 = *(const float4*)(bw2 + r * NH + cb + 12);
        const float vv[16] = {v0.x,v0.y,v0.z,v0.w,v1.x,v1.y,v1.z,v1.w,
                              v2.x,v2.y,v2.z,v2.w,v3.x,v3.y,v3.z,v3.w};
#pragma unroll
        for (int j = 0; j < 16; ++j) bw2s[r][cb + j] = vv[j];
    }
    if (tid < 64) {
        float4 zv = *(const float4*)(z + ((size_t)b * NZ + tid) * NK + k0);
        zs[tid][0] = zv.x; zs[tid][1] = zv.y; zs[tid][2] = zv.z; zs[tid][3] = zv.w;
    }
    if (tid < 32) { b1s[tid] = b1[tid]; bb1s[tid] = bb1[tid]; }
    if (tid >= 128 && tid < 256) bb2s[tid - 128] = bb2[tid - 128];
    __syncthreads();

    int chunk = chunk0 + w;
    if (lane < NH) {
        float s = b1s[lane];
#pragma unroll
        for (int i = 0; i < NZ; ++i) s = fmaf(w1sT[i][lane], zs[i][w], s);
        Hb[(size_t)chunk * NH + lane] = f2bf(fmaxf(s, 0.f));
    } else {
        int j = lane - NH;
        float s = bb1s[j];
#pragma unroll
        for (int i = 0; i < NZ; ++i) s = fmaf(bw1sT[i][j], zs[i][w], s);
        hbs[w][j] = fmaxf(s, 0.f);
    }

#pragma unroll
    for (int r = 0; r < 2; ++r) {
        int c = r * 64 + lane;
        float s = bb2s[c];
#pragma unroll
        for (int j = 0; j < NH; ++j) s = fmaf(bw2s[c][j], hbs[w][j], s);
        biasws[(size_t)chunk * NC + c] = s;
    }
}

// ---------------------------------------------------------------------------
// k2: MFMA weight materialization, v3 — k0w fused into prologue.
// Block = 256 m' slice; afrag gathered ONCE directly from w2 (f32, permuted
// index m = a*128+c; L2-resident 6.3 MB) and held in registers across a
// 10-group chunk loop. Bit-identical to the old k0w+k2 path.
// ---------------------------------------------------------------------------
__global__ __launch_bounds__(256) void k2_wgen(
    const float* __restrict__ w2, const float* __restrict__ b2,
    const uint16_t* __restrict__ Hb, uint16_t* __restrict__ Wt,
    int chunk0, int nchunk) {
    int tid = threadIdx.x, lane = tid & 63, w = tid >> 6;
    int quad = lane >> 4, li = lane & 15;
    __shared__ __align__(16) uint16_t St[4][16][68];   // pad 64->68
    int mb = blockIdx.x * 256 + w * 64;                // wave's m' base

    bf16x8 afrag[4];   // loop-invariant A tiles (registers)
    float4 bias[4];
#pragma unroll
    for (int t = 0; t < 4; ++t) {
        int mp = mb + t * 16 + li;                     // m' = c*384 + a
        int a = mp % NA, c = mp / NA;
        const float* src = w2 + ((size_t)a * NC + c) * NH + quad * 8;
        float4 v0 = *(const float4*)(src);
        float4 v1 = *(const float4*)(src + 4);
        uint16_t tmp[8] = { f2bf(v0.x), f2bf(v0.y), f2bf(v0.z), f2bf(v0.w),
                            f2bf(v1.x), f2bf(v1.y), f2bf(v1.z), f2bf(v1.w) };
        __builtin_memcpy(&afrag[t], tmp, 16);
        float bv[4];
#pragma unroll
        for (int r = 0; r < 4; ++r) {
            int mpr = mb + t * 16 + quad * 4 + r;
            bv[r] = b2[(size_t)(mpr % NA) * NC + (mpr / NA)];
        }
        bias[t] = make_float4(bv[0], bv[1], bv[2], bv[3]);
    }

    for (int g = 0; g < 10; ++g) {
        int cl0 = blockIdx.y * 160 + g * 16;           // local chunk base
        if (cl0 >= nchunk) break;
        int cl = cl0 + li;
        if (cl >= nchunk) cl = nchunk - 1;
        bf16x8 hfrag = *(const bf16x8*)(Hb + (size_t)(chunk0 + cl) * NH + quad * 8);
#pragma unroll
        for (int t = 0; t < 4; ++t) {
            f32x4 acc = {0.f, 0.f, 0.f, 0.f};
            acc = __builtin_amdgcn_mfma_f32_16x16x32_bf16(afrag[t], hfrag, acc, 0, 0, 0);
            uint16_t p[4] = { f2bf(acc[0] + bias[t].x), f2bf(acc[1] + bias[t].y),
                              f2bf(acc[2] + bias[t].z), f2bf(acc[3] + bias[t].w) };
            uint64_t pv; __builtin_memcpy(&pv, p, 8);
            *(uint64_t*)&St[w][li][t * 16 + quad * 4] = pv;
        }
        // same-wave readback (compiler inserts lgkmcnt wait) + coalesced store
#pragma unroll
        for (int p = 0; p < 2; ++p) {
            int ch = (lane >> 3) + p * 8, part = lane & 7;
            uint4 v = *(const uint4*)&St[w][ch][part * 8];
            int cg = cl0 + ch;
            if (cg < nchunk)
                *(uint4*)(Wt + (size_t)cg * MW + mb + part * 8) = v;
        }
    }
}

// ---------------------------------------------------------------------------
// k3: per-chunk conv GEMM, v4 — tri-buffered W stage with counted vmcnt.
// The dbuf version's stage had only ~160 cyc of MFMA cover vs 300-500 cyc
// L2/L3 latency, and __syncthreads' vmcnt(0) drained the lookahead. Now:
// 3 W buffers, stage D(dk+2) issued right after the barrier, and the wait
// is `s_waitcnt vmcnt(4)` (leaves D(dk+1)'s 4 loads in flight). Underwait
// is impossible: when the wait executes, D(dk)'s loads are >=5 deep in the
// per-wave VMEM queue (vmcnt retires in issue order). Barrier then makes
// all waves' D(dk) writes visible. LDS 32+3*16=80 KB -> 2 blocks/CU.
// ---------------------------------------------------------------------------
__global__ __launch_bounds__(256) void k3_conv(
    const uint16_t* __restrict__ Xt, const uint16_t* __restrict__ Wt,
    const float* __restrict__ biasws, float* __restrict__ out, int chunk0) {
    int cl = blockIdx.x, chunk = chunk0 + cl;
    int b = chunk / NK, k = chunk - b * NK;
    int kbase = k * TK;
    int tid = threadIdx.x, lane = tid & 63, w = tid >> 6;
    int quad = lane >> 4, li = lane & 15;
    int tblk = (w & 1) * 64, cblk = (w >> 1) * 64;

    __shared__ __align__(16) char smem[81920];
    char* Xa  = smem;             // 128 rows x 256B (cin-unit XOR-swizzled)
    char* Db0 = smem + 32768;     // W tri-buf: [c 128][8 slot^(c&7)][8a] =16KB
    char* Db1 = smem + 49152;
    char* Db2 = smem + 65536;
    const uint16_t* XtB = Xt + (size_t)b * XROWS * NC;
    const uint16_t* WtC = Wt + (size_t)cl * MW;

    f32x4 acc[4][4];
#pragma unroll
    for (int i = 0; i < 4; ++i)
#pragma unroll
        for (int j = 0; j < 4; ++j) acc[i][j] = (f32x4){0.f, 0.f, 0.f, 0.f};

    // stage of W for one dk: 16 insts/block (4/wave), each 8x128B source runs
    auto stageD = [&](char* dst, int dks) {
#pragma unroll
        for (int j = 0; j < 4; ++j) {
            int g = (w * 4 + j) * 64 + lane;          // 16B-unit index 0..1023
            int c = g >> 3, sd = g & 7;               // 8 units per c
            int o = sd ^ (c & 7);                     // inverse slot swizzle
            const uint16_t* gsrc = WtC + (size_t)c * NA + dks * 64 + o * 8;
            __builtin_amdgcn_global_load_lds(
                (__attribute__((address_space(1))) void*)gsrc,
                (__attribute__((address_space(3))) void*)(dst + (w * 4 + j) * 1024),
                16, 0, 0);
        }
    };

    // prologue: Xa (8/wave) + D0 (4/wave) + D1 (4/wave) -> 16 outstanding
#pragma unroll
    for (int i = 0; i < 8; ++i) {
        int brow = w * 32 + i * 4 + quad;
        const uint16_t* g = XtB + (size_t)(kbase + brow) * NC
                          + ((li ^ (brow & 15)) * 8);
        __builtin_amdgcn_global_load_lds(
            (__attribute__((address_space(1))) void*)g,
            (__attribute__((address_space(3))) void*)(Xa + (w * 32 + i * 4) * 256),
            16, 0, 0);
    }
    stageD(Db0, 0);
    stageD(Db1, 1);

#pragma unroll
    for (int dk = 0; dk < 6; ++dk) {
        // wait own D(dk) loads (leave D(dk+1)'s 4 in flight), then barrier:
        // all waves' D(dk) (+Xa at dk=0) writes visible.
        if (dk < 5) asm volatile("s_waitcnt vmcnt(4)" ::: "memory");
        else        asm volatile("s_waitcnt vmcnt(0)" ::: "memory");
        __builtin_amdgcn_s_barrier();
        __builtin_amdgcn_sched_barrier(0);
        if (dk < 4) {   // issue D(dk+2) into the buffer read at dk-1
            int sel = (dk + 2) % 3;
            stageD(sel == 0 ? Db0 : (sel == 1 ? Db1 : Db2), dk + 2);
        }
        int cs = dk % 3;
        char* cur = cs == 0 ? Db0 : (cs == 1 ? Db1 : Db2);
        int tap = dk >> 1;

        bf16x8 bfr[2][4];
#pragma unroll
        for (int s = 0; s < 2; ++s)
#pragma unroll
            for (int ct = 0; ct < 4; ++ct) {
                int c = cblk + ct * 16 + li;
                bfr[s][ct] = *(const bf16x8*)(cur + c * 128
                             + (((s * 4 + quad) ^ (c & 7)) << 4));
            }
#pragma unroll
        for (int s = 0; s < 2; ++s) {
            bf16x8 af[4];
#pragma unroll
            for (int tt = 0; tt < 4; ++tt) {
                int r = tblk + tt * 16 + li + 2 - tap;
                r = r > 127 ? 127 : r;     // clamped rows feed only discarded t
                int q = (dk & 1) * 8 + s * 4 + quad;
                af[tt] = *(const bf16x8*)(Xa + r * 256 + ((q ^ (r & 15)) << 4));
            }
#pragma unroll
            for (int tt = 0; tt < 4; ++tt)
#pragma unroll
                for (int ct = 0; ct < 4; ++ct)
                    acc[tt][ct] = __builtin_amdgcn_mfma_f32_16x16x32_bf16(
                        af[tt], bfr[s][ct], acc[tt][ct], 0, 0, 0);
        }
    }

    // epilogue: D col = c = lane&15 (+tile), row = t = quad*4+reg (+tile)
#pragma unroll
    for (int ct = 0; ct < 4; ++ct) {
        int c = cblk + ct * 16 + li;
        float bias = biasws[(size_t)chunk * NC + c];
        float* ob = out + ((size_t)b * NC + c) * TT + kbase;
#pragma unroll
        for (int tt = 0; tt < 4; ++tt) {
            int t0v = tblk + tt * 16 + quad * 4;
            if (t0v < TK) {
                f32x4 v = acc[tt][ct];
                *(float4*)(ob + t0v) = make_float4(v[0] + bias, v[1] + bias,
                                                   v[2] + bias, v[3] + bias);
            }
        }
    }
}

// ---------------------------------------------------------------------------
// launch
// ---------------------------------------------------------------------------
extern "C" void kernel_launch(void* const* d_in, const int* in_sizes, int n_in,
                              void* d_out, int out_size, void* d_ws, size_t ws_size,
                              hipStream_t stream) {
    const float* x   = (const float*)d_in[0];
    const float* z   = (const float*)d_in[1];
    const float* w1  = (const float*)d_in[2];
    const float* b1  = (const float*)d_in[3];
    const float* w2  = (const float*)d_in[4];
    const float* b2  = (const float*)d_in[5];
    const float* bw1 = (const float*)d_in[6];
    const float* bb1 = (const float*)d_in[7];
    const float* bw2 = (const float*)d_in[8];
    const float* bb2 = (const float*)d_in[9];
    float* out = (float*)d_out;

    // ws layout (all 256-aligned):
    char* ws = (char*)d_ws;
    uint16_t* Hb     = (uint16_t*)(ws);                 //   102,400 B
    float*    biasws = (float*)(ws + 102400);           //   819,200 B
    uint16_t* Xt     = (uint16_t*)(ws + 921600);        // 49,158,144 B (incl. tail pad)
    const size_t wt_off = 50079744;
    uint16_t* Wt     = (uint16_t*)(ws + wt_off);        // up to 157 MB

    // Single batch if ws permits (1600 chunks -> 157 MB Wt; L3 = 256 MB
    // keeps the k2->k3 hop cache-resident). Falls back to smaller batches.
    size_t avail = (ws_size > wt_off) ? (ws_size - wt_off) : 0;
    int batch = (int)(avail / ((size_t)MW * 2));
    if (batch > NCHUNK) batch = NCHUNK;
    if (batch < 1) batch = 1;

    k0x<<<dim3(TT / 128, 2, 4), 256, 0, stream>>>(x, Xt);
    k1_hidden<<<NCHUNK / 4, 256, 0, stream>>>(z, w1, b1, bw1, bb1, bw2, bb2, Hb, biasws);

    for (int c0 = 0; c0 < NCHUNK; c0 += batch) {
        int nc = NCHUNK - c0;
        if (nc > batch) nc = batch;
        dim3 g2(MW / 256, (nc + 159) / 160, 1);
        k2_wgen<<<g2, 256, 0, stream>>>(w2, b2, Hb, Wt, c0, nc);
        k3_conv<<<nc, 256, 0, stream>>>(Xt, Wt, biasws, out, c0);
    }
}

// Round 7
// 291.172 us; speedup vs baseline: 1.0285x; 1.0285x over previous
//
#include <hip/hip_runtime.h>
#include <stdint.h>

// Problem constants
#define TT     48000   // T
#define TK     120     // samples per chunk (T/K)
#define NC     128     // CIN == COUT
#define NA     384     // CIN*KS
#define NZ     64
#define NH     32
#define NK     400
#define NCHUNK 1600    // B*K
#define MW     49152   // CIN*COUT*KS
#define XROWS  48002   // T + 2 zero prefix rows (causal taps)

typedef float f32x4 __attribute__((ext_vector_type(4)));
typedef __bf16 bf16x8 __attribute__((ext_vector_type(8)));

static __device__ __forceinline__ uint16_t f2bf(float f) {
    uint32_t x; __builtin_memcpy(&x, &f, 4);
    return (uint16_t)((x + 0x7fffu + ((x >> 16) & 1u)) >> 16);
}

// ---------------------------------------------------------------------------
// k0x: transpose x[b][cin][t] f32 -> Xt[b][t+2][cin] bf16 (2 zero prefix rows)
// tile: 128 t x 64 cin per block
// ---------------------------------------------------------------------------
__global__ __launch_bounds__(256) void k0x(
    const float* __restrict__ x, uint16_t* __restrict__ Xt) {
    int t0 = blockIdx.x * 128, cin0 = blockIdx.y * 64, b = blockIdx.z;
    int tid = threadIdx.x;
    __shared__ __align__(16) uint16_t Lt[128][72];   // pad row to 72 (144B)
    const float* xb = x + ((size_t)b * NC + cin0) * TT + t0;
    int cg = (tid & 7) * 8;    // local cin base (0..56)
    int tq = (tid >> 3) * 4;   // local t base   (0..124)
    uint16_t vb[4][8];         // [t][cin]
#pragma unroll
    for (int i = 0; i < 8; ++i) {
        float4 v = *(const float4*)(xb + (size_t)(cg + i) * TT + tq);
        vb[0][i] = f2bf(v.x); vb[1][i] = f2bf(v.y);
        vb[2][i] = f2bf(v.z); vb[3][i] = f2bf(v.w);
    }
#pragma unroll
    for (int j = 0; j < 4; ++j) {
        uint4 o; __builtin_memcpy(&o, vb[j], 16);
        *(uint4*)&Lt[tq + j][cg] = o;
    }
    __syncthreads();
    uint16_t* XtB = Xt + (size_t)b * XROWS * NC;
#pragma unroll
    for (int r = 0; r < 4; ++r) {
        int s = r * 256 + tid;
        int t = s >> 3, cc = s & 7;
        uint4 o = *(uint4*)&Lt[t][cc * 8];
        *(uint4*)(XtB + (size_t)(t0 + t + 2) * NC + cin0 + cc * 8) = o;
    }
    if (blockIdx.x == 0 && blockIdx.y == 0 && tid < 32)
        *(uint4*)(XtB + tid * 8) = make_uint4(0, 0, 0, 0);  // zero rows -2,-1
}

// ---------------------------------------------------------------------------
// k1: 4 chunks per block (one per wave). All weights staged in LDS with
// conflict-free layouts; coalesced global loads.
// ---------------------------------------------------------------------------
__global__ __launch_bounds__(256) void k1_hidden(
    const float* __restrict__ z,
    const float* __restrict__ w1, const float* __restrict__ b1,
    const float* __restrict__ bw1, const float* __restrict__ bb1,
    const float* __restrict__ bw2, const float* __restrict__ bb2,
    uint16_t* __restrict__ Hb, float* __restrict__ biasws) {
    int tid = threadIdx.x, lane = tid & 63, w = tid >> 6;
    int chunk0 = blockIdx.x * 4;
    int b = chunk0 / NK;            // 400 % 4 == 0: all 4 chunks same b
    int k0 = chunk0 - b * NK;

    __shared__ float w1sT[64][33];   // [i][h] transposed, conflict-free reads
    __shared__ float bw1sT[64][33];
    __shared__ float bw2s[128][33];  // [c][j]
    __shared__ float zs[64][4];
    __shared__ float hbs[4][33];
    __shared__ float b1s[32], bb1s[32], bb2s[128];

    {   // stage w1, bw1 (transposed)
        int row = tid >> 3, c0 = (tid & 7) * 8;
        float4 a0 = *(const float4*)(w1 + row * NZ + c0);
        float4 a1 = *(const float4*)(w1 + row * NZ + c0 + 4);
        float4 c0v = *(const float4*)(bw1 + row * NZ + c0);
        float4 c1v = *(const float4*)(bw1 + row * NZ + c0 + 4);
        const float av[8] = {a0.x,a0.y,a0.z,a0.w,a1.x,a1.y,a1.z,a1.w};
        const float cv[8] = {c0v.x,c0v.y,c0v.z,c0v.w,c1v.x,c1v.y,c1v.z,c1v.w};
#pragma unroll
        for (int j = 0; j < 8; ++j) {
            w1sT[c0 + j][row]  = av[j];
            bw1sT[c0 + j][row] = cv[j];
        }
    }
    {   // stage bw2 [128][32]
        int r = tid >> 1, cb = (tid & 1) * 16;
        float4 v0 = *(const float4*)(bw2 + r * NH + cb);
        float4 v1 = *(const float4*)(bw2 + r * NH + cb + 4);
        float4 v2 = *(const float4*)(bw2 + r * NH + cb + 8);
        float4 v3 = *(const float4*)(bw2 + r * NH + cb + 12);
        const float vv[16] = {v0.x,v0.y,v0.z,v0.w,v1.x,v1.y,v1.z,v1.w,
                              v2.x,v2.y,v2.z,v2.w,v3.x,v3.y,v3.z,v3.w};
#pragma unroll
        for (int j = 0; j < 16; ++j) bw2s[r][cb + j] = vv[j];
    }
    if (tid < 64) {
        float4 zv = *(const float4*)(z + ((size_t)b * NZ + tid) * NK + k0);
        zs[tid][0] = zv.x; zs[tid][1] = zv.y; zs[tid][2] = zv.z; zs[tid][3] = zv.w;
    }
    if (tid < 32) { b1s[tid] = b1[tid]; bb1s[tid] = bb1[tid]; }
    if (tid >= 128 && tid < 256) bb2s[tid - 128] = bb2[tid - 128];
    __syncthreads();

    int chunk = chunk0 + w;
    if (lane < NH) {
        float s = b1s[lane];
#pragma unroll
        for (int i = 0; i < NZ; ++i) s = fmaf(w1sT[i][lane], zs[i][w], s);
        Hb[(size_t)chunk * NH + lane] = f2bf(fmaxf(s, 0.f));
    } else {
        int j = lane - NH;
        float s = bb1s[j];
#pragma unroll
        for (int i = 0; i < NZ; ++i) s = fmaf(bw1sT[i][j], zs[i][w], s);
        hbs[w][j] = fmaxf(s, 0.f);
    }

#pragma unroll
    for (int r = 0; r < 2; ++r) {
        int c = r * 64 + lane;
        float s = bb2s[c];
#pragma unroll
        for (int j = 0; j < NH; ++j) s = fmaf(bw2s[c][j], hbs[w][j], s);
        biasws[(size_t)chunk * NC + c] = s;
    }
}

// ---------------------------------------------------------------------------
// k2: MFMA weight materialization (k0w fused into prologue; verified r6).
// Block = 256 m' slice; afrag gathered ONCE directly from w2 (permuted
// index m = a*128+c; L2-resident 6.3 MB) and held in registers across a
// 10-group chunk loop. Bit-identical to the old k0w+k2 path.
// ---------------------------------------------------------------------------
__global__ __launch_bounds__(256) void k2_wgen(
    const float* __restrict__ w2, const float* __restrict__ b2,
    const uint16_t* __restrict__ Hb, uint16_t* __restrict__ Wt,
    int chunk0, int nchunk) {
    int tid = threadIdx.x, lane = tid & 63, w = tid >> 6;
    int quad = lane >> 4, li = lane & 15;
    __shared__ __align__(16) uint16_t St[4][16][68];   // pad 64->68
    int mb = blockIdx.x * 256 + w * 64;                // wave's m' base

    bf16x8 afrag[4];   // loop-invariant A tiles (registers)
    float4 bias[4];
#pragma unroll
    for (int t = 0; t < 4; ++t) {
        int mp = mb + t * 16 + li;                     // m' = c*384 + a
        int a = mp % NA, c = mp / NA;
        const float* src = w2 + ((size_t)a * NC + c) * NH + quad * 8;
        float4 v0 = *(const float4*)(src);
        float4 v1 = *(const float4*)(src + 4);
        uint16_t tmp[8] = { f2bf(v0.x), f2bf(v0.y), f2bf(v0.z), f2bf(v0.w),
                            f2bf(v1.x), f2bf(v1.y), f2bf(v1.z), f2bf(v1.w) };
        __builtin_memcpy(&afrag[t], tmp, 16);
        float bv[4];
#pragma unroll
        for (int r = 0; r < 4; ++r) {
            int mpr = mb + t * 16 + quad * 4 + r;
            bv[r] = b2[(size_t)(mpr % NA) * NC + (mpr / NA)];
        }
        bias[t] = make_float4(bv[0], bv[1], bv[2], bv[3]);
    }

    for (int g = 0; g < 10; ++g) {
        int cl0 = blockIdx.y * 160 + g * 16;           // local chunk base
        if (cl0 >= nchunk) break;
        int cl = cl0 + li;
        if (cl >= nchunk) cl = nchunk - 1;
        bf16x8 hfrag = *(const bf16x8*)(Hb + (size_t)(chunk0 + cl) * NH + quad * 8);
#pragma unroll
        for (int t = 0; t < 4; ++t) {
            f32x4 acc = {0.f, 0.f, 0.f, 0.f};
            acc = __builtin_amdgcn_mfma_f32_16x16x32_bf16(afrag[t], hfrag, acc, 0, 0, 0);
            uint16_t p[4] = { f2bf(acc[0] + bias[t].x), f2bf(acc[1] + bias[t].y),
                              f2bf(acc[2] + bias[t].z), f2bf(acc[3] + bias[t].w) };
            uint64_t pv; __builtin_memcpy(&pv, p, 8);
            *(uint64_t*)&St[w][li][t * 16 + quad * 4] = pv;
        }
        // same-wave readback (compiler inserts lgkmcnt wait) + coalesced store
#pragma unroll
        for (int p = 0; p < 2; ++p) {
            int ch = (lane >> 3) + p * 8, part = lane & 7;
            uint4 v = *(const uint4*)&St[w][ch][part * 8];
            int cg = cl0 + ch;
            if (cg < nchunk)
                *(uint4*)(Wt + (size_t)cg * MW + mb + part * 8) = v;
        }
    }
}

// ---------------------------------------------------------------------------
// k3: per-chunk conv GEMM, v5 — 512 threads / 8 waves (was 256/4).
// Round-6 PMC: 64 µs, 3.1 TB/s, Occupancy 15%, MfmaUtil 11% -> traffic/
// latency-bound with too few waves/CU (80 KB LDS x 256-thr = 8 waves/CU
// ceiling). Same 80 KB tri-buffer counted-vmcnt pipeline, but 8 waves/block
// -> 16 waves/CU ceiling (2 blocks x 80 KB = 160 KB exactly). Wave-tile
// 32t x 64c (acc 2x4). Per-wave: Xa 4 + D 2 stage insts; vmcnt leaves the
// next D's 2 loads in flight. Numerics bit-identical.
// ---------------------------------------------------------------------------
__global__ __launch_bounds__(512) void k3_conv(
    const uint16_t* __restrict__ Xt, const uint16_t* __restrict__ Wt,
    const float* __restrict__ biasws, float* __restrict__ out, int chunk0) {
    int cl = blockIdx.x, chunk = chunk0 + cl;
    int b = chunk / NK, k = chunk - b * NK;
    int kbase = k * TK;
    int tid = threadIdx.x, lane = tid & 63, w = tid >> 6;   // w 0..7
    int quad = lane >> 4, li = lane & 15;
    int tblk = (w >> 1) * 32, cblk = (w & 1) * 64;

    __shared__ __align__(16) char smem[81920];
    char* Xa  = smem;             // 128 rows x 256B (cin-unit XOR-swizzled)
    char* Db0 = smem + 32768;     // W tri-buf: [c 128][8 slot^(c&7)][8a] =16KB
    char* Db1 = smem + 49152;
    char* Db2 = smem + 65536;
    const uint16_t* XtB = Xt + (size_t)b * XROWS * NC;
    const uint16_t* WtC = Wt + (size_t)cl * MW;

    f32x4 acc[2][4];
#pragma unroll
    for (int i = 0; i < 2; ++i)
#pragma unroll
        for (int j = 0; j < 4; ++j) acc[i][j] = (f32x4){0.f, 0.f, 0.f, 0.f};

    // stage of W for one dk: 16 insts/block (2/wave), each 8x128B source runs
    auto stageD = [&](char* dst, int dks) {
#pragma unroll
        for (int j = 0; j < 2; ++j) {
            int g = (w * 2 + j) * 64 + lane;          // 16B-unit index 0..1023
            int c = g >> 3, sd = g & 7;               // 8 units per c
            int o = sd ^ (c & 7);                     // inverse slot swizzle
            const uint16_t* gsrc = WtC + (size_t)c * NA + dks * 64 + o * 8;
            __builtin_amdgcn_global_load_lds(
                (__attribute__((address_space(1))) void*)gsrc,
                (__attribute__((address_space(3))) void*)(dst + (w * 2 + j) * 1024),
                16, 0, 0);
        }
    };

    // prologue: Xa (4/wave) + D0 (2/wave) + D1 (2/wave) -> 8 outstanding
#pragma unroll
    for (int i = 0; i < 4; ++i) {
        int brow = w * 16 + i * 4 + quad;
        const uint16_t* g = XtB + (size_t)(kbase + brow) * NC
                          + ((li ^ (brow & 15)) * 8);
        __builtin_amdgcn_global_load_lds(
            (__attribute__((address_space(1))) void*)g,
            (__attribute__((address_space(3))) void*)(Xa + (w * 16 + i * 4) * 256),
            16, 0, 0);
    }
    stageD(Db0, 0);
    stageD(Db1, 1);

#pragma unroll
    for (int dk = 0; dk < 6; ++dk) {
        // wait own D(dk) loads (leave D(dk+1)'s 2 in flight), then barrier:
        // all waves' D(dk) (+Xa at dk=0) writes visible.
        if (dk < 5) asm volatile("s_waitcnt vmcnt(2)" ::: "memory");
        else        asm volatile("s_waitcnt vmcnt(0)" ::: "memory");
        __builtin_amdgcn_s_barrier();
        __builtin_amdgcn_sched_barrier(0);
        if (dk < 4) {   // issue D(dk+2) into the buffer read at dk-1
            int sel = (dk + 2) % 3;
            stageD(sel == 0 ? Db0 : (sel == 1 ? Db1 : Db2), dk + 2);
        }
        int cs = dk % 3;
        char* cur = cs == 0 ? Db0 : (cs == 1 ? Db1 : Db2);
        int tap = dk >> 1;

        bf16x8 bfr[2][4];
#pragma unroll
        for (int s = 0; s < 2; ++s)
#pragma unroll
            for (int ct = 0; ct < 4; ++ct) {
                int c = cblk + ct * 16 + li;
                bfr[s][ct] = *(const bf16x8*)(cur + c * 128
                             + (((s * 4 + quad) ^ (c & 7)) << 4));
            }
#pragma unroll
        for (int s = 0; s < 2; ++s) {
            bf16x8 af[2];
#pragma unroll
            for (int tt = 0; tt < 2; ++tt) {
                int r = tblk + tt * 16 + li + 2 - tap;
                r = r > 127 ? 127 : r;     // clamped rows feed only discarded t
                int q = (dk & 1) * 8 + s * 4 + quad;
                af[tt] = *(const bf16x8*)(Xa + r * 256 + ((q ^ (r & 15)) << 4));
            }
#pragma unroll
            for (int tt = 0; tt < 2; ++tt)
#pragma unroll
                for (int ct = 0; ct < 4; ++ct)
                    acc[tt][ct] = __builtin_amdgcn_mfma_f32_16x16x32_bf16(
                        af[tt], bfr[s][ct], acc[tt][ct], 0, 0, 0);
        }
    }

    // epilogue: D col = c = lane&15 (+tile), row = t = quad*4+reg (+tile)
#pragma unroll
    for (int ct = 0; ct < 4; ++ct) {
        int c = cblk + ct * 16 + li;
        float bias = biasws[(size_t)chunk * NC + c];
        float* ob = out + ((size_t)b * NC + c) * TT + kbase;
#pragma unroll
        for (int tt = 0; tt < 2; ++tt) {
            int t0v = tblk + tt * 16 + quad * 4;
            if (t0v < TK) {
                f32x4 v = acc[tt][ct];
                *(float4*)(ob + t0v) = make_float4(v[0] + bias, v[1] + bias,
                                                   v[2] + bias, v[3] + bias);
            }
        }
    }
}

// ---------------------------------------------------------------------------
// launch
// ---------------------------------------------------------------------------
extern "C" void kernel_launch(void* const* d_in, const int* in_sizes, int n_in,
                              void* d_out, int out_size, void* d_ws, size_t ws_size,
                              hipStream_t stream) {
    const float* x   = (const float*)d_in[0];
    const float* z   = (const float*)d_in[1];
    const float* w1  = (const float*)d_in[2];
    const float* b1  = (const float*)d_in[3];
    const float* w2  = (const float*)d_in[4];
    const float* b2  = (const float*)d_in[5];
    const float* bw1 = (const float*)d_in[6];
    const float* bb1 = (const float*)d_in[7];
    const float* bw2 = (const float*)d_in[8];
    const float* bb2 = (const float*)d_in[9];
    float* out = (float*)d_out;

    // ws layout (all 256-aligned):
    char* ws = (char*)d_ws;
    uint16_t* Hb     = (uint16_t*)(ws);                 //   102,400 B
    float*    biasws = (float*)(ws + 102400);           //   819,200 B
    uint16_t* Xt     = (uint16_t*)(ws + 921600);        // 49,158,144 B (incl. tail pad)
    const size_t wt_off = 50079744;
    uint16_t* Wt     = (uint16_t*)(ws + wt_off);        // slice buffer

    // L3 blocking restored (round-6 PMC: single 157 MB Wt spilled L3 ->
    // 54 MB HBM re-fetch in k3). 800 chunks -> 78.6 MB slice;
    // 78 Wt + 49 Xt + 98 out < 256 MB L3.
    size_t avail = (ws_size > wt_off) ? (ws_size - wt_off) : 0;
    int batch = (int)(avail / ((size_t)MW * 2));
    if (batch > 800) batch = 800;
    if (batch < 1) batch = 1;

    k0x<<<dim3(TT / 128, 2, 4), 256, 0, stream>>>(x, Xt);
    k1_hidden<<<NCHUNK / 4, 256, 0, stream>>>(z, w1, b1, bw1, bb1, bw2, bb2, Hb, biasws);

    for (int c0 = 0; c0 < NCHUNK; c0 += batch) {
        int nc = NCHUNK - c0;
        if (nc > batch) nc = batch;
        dim3 g2(MW / 256, (nc + 159) / 160, 1);
        k2_wgen<<<g2, 256, 0, stream>>>(w2, b2, Hb, Wt, c0, nc);
        k3_conv<<<nc, 512, 0, stream>>>(Xt, Wt, biasws, out, c0);
    }
}

// Round 8
// 284.482 us; speedup vs baseline: 1.0527x; 1.0235x over previous
//
#include <hip/hip_runtime.h>
#include <stdint.h>

// Problem constants
#define TT     48000   // T
#define TK     120     // samples per chunk (T/K)
#define NC     128     // CIN == COUT
#define NA     384     // CIN*KS
#define NZ     64
#define NH     32
#define NK     400
#define NCHUNK 1600    // B*K
#define MW     49152   // CIN*COUT*KS

typedef float f32x4 __attribute__((ext_vector_type(4)));
typedef __bf16 bf16x8 __attribute__((ext_vector_type(8)));

static __device__ __forceinline__ uint16_t f2bf(float f) {
    uint32_t x; __builtin_memcpy(&x, &f, 4);
    return (uint16_t)((x + 0x7fffu + ((x >> 16) & 1u)) >> 16);
}
static __device__ __forceinline__ uint32_t pk2u(uint16_t lo, uint16_t hi) {
    return (uint32_t)lo | ((uint32_t)hi << 16);
}

// ---------------------------------------------------------------------------
// k1: 4 chunks per block (one per wave). All weights staged in LDS with
// conflict-free layouts; coalesced global loads.
// ---------------------------------------------------------------------------
__global__ __launch_bounds__(256) void k1_hidden(
    const float* __restrict__ z,
    const float* __restrict__ w1, const float* __restrict__ b1,
    const float* __restrict__ bw1, const float* __restrict__ bb1,
    const float* __restrict__ bw2, const float* __restrict__ bb2,
    uint16_t* __restrict__ Hb, float* __restrict__ biasws) {
    int tid = threadIdx.x, lane = tid & 63, w = tid >> 6;
    int chunk0 = blockIdx.x * 4;
    int b = chunk0 / NK;            // 400 % 4 == 0: all 4 chunks same b
    int k0 = chunk0 - b * NK;

    __shared__ float w1sT[64][33];   // [i][h] transposed, conflict-free reads
    __shared__ float bw1sT[64][33];
    __shared__ float bw2s[128][33];  // [c][j]
    __shared__ float zs[64][4];
    __shared__ float hbs[4][33];
    __shared__ float b1s[32], bb1s[32], bb2s[128];

    {   // stage w1, bw1 (transposed)
        int row = tid >> 3, c0 = (tid & 7) * 8;
        float4 a0 = *(const float4*)(w1 + row * NZ + c0);
        float4 a1 = *(const float4*)(w1 + row * NZ + c0 + 4);
        float4 c0v = *(const float4*)(bw1 + row * NZ + c0);
        float4 c1v = *(const float4*)(bw1 + row * NZ + c0 + 4);
        const float av[8] = {a0.x,a0.y,a0.z,a0.w,a1.x,a1.y,a1.z,a1.w};
        const float cv[8] = {c0v.x,c0v.y,c0v.z,c0v.w,c1v.x,c1v.y,c1v.z,c1v.w};
#pragma unroll
        for (int j = 0; j < 8; ++j) {
            w1sT[c0 + j][row]  = av[j];
            bw1sT[c0 + j][row] = cv[j];
        }
    }
    {   // stage bw2 [128][32]
        int r = tid >> 1, cb = (tid & 1) * 16;
        float4 v0 = *(const float4*)(bw2 + r * NH + cb);
        float4 v1 = *(const float4*)(bw2 + r * NH + cb + 4);
        float4 v2 = *(const float4*)(bw2 + r * NH + cb + 8);
        float4 v3 = *(const float4*)(bw2 + r * NH + cb + 12);
        const float vv[16] = {v0.x,v0.y,v0.z,v0.w,v1.x,v1.y,v1.z,v1.w,
                              v2.x,v2.y,v2.z,v2.w,v3.x,v3.y,v3.z,v3.w};
#pragma unroll
        for (int j = 0; j < 16; ++j) bw2s[r][cb + j] = vv[j];
    }
    if (tid < 64) {
        float4 zv = *(const float4*)(z + ((size_t)b * NZ + tid) * NK + k0);
        zs[tid][0] = zv.x; zs[tid][1] = zv.y; zs[tid][2] = zv.z; zs[tid][3] = zv.w;
    }
    if (tid < 32) { b1s[tid] = b1[tid]; bb1s[tid] = bb1[tid]; }
    if (tid >= 128 && tid < 256) bb2s[tid - 128] = bb2[tid - 128];
    __syncthreads();

    int chunk = chunk0 + w;
    if (lane < NH) {
        float s = b1s[lane];
#pragma unroll
        for (int i = 0; i < NZ; ++i) s = fmaf(w1sT[i][lane], zs[i][w], s);
        Hb[(size_t)chunk * NH + lane] = f2bf(fmaxf(s, 0.f));
    } else {
        int j = lane - NH;
        float s = bb1s[j];
#pragma unroll
        for (int i = 0; i < NZ; ++i) s = fmaf(bw1sT[i][j], zs[i][w], s);
        hbs[w][j] = fmaxf(s, 0.f);
    }

#pragma unroll
    for (int r = 0; r < 2; ++r) {
        int c = r * 64 + lane;
        float s = bb2s[c];
#pragma unroll
        for (int j = 0; j < NH; ++j) s = fmaf(bw2s[c][j], hbs[w][j], s);
        biasws[(size_t)chunk * NC + c] = s;
    }
}

// ---------------------------------------------------------------------------
// k2: MFMA weight materialization (k0w fused into prologue; verified r6/r7).
// Block = 256 m' slice; afrag gathered ONCE directly from w2 (permuted
// index m = a*128+c; L2-resident 6.3 MB) and held in registers across a
// 10-group chunk loop. Bit-identical to the old k0w+k2 path.
// ---------------------------------------------------------------------------
__global__ __launch_bounds__(256) void k2_wgen(
    const float* __restrict__ w2, const float* __restrict__ b2,
    const uint16_t* __restrict__ Hb, uint16_t* __restrict__ Wt,
    int chunk0, int nchunk) {
    int tid = threadIdx.x, lane = tid & 63, w = tid >> 6;
    int quad = lane >> 4, li = lane & 15;
    __shared__ __align__(16) uint16_t St[4][16][68];   // pad 64->68
    int mb = blockIdx.x * 256 + w * 64;                // wave's m' base

    bf16x8 afrag[4];   // loop-invariant A tiles (registers)
    float4 bias[4];
#pragma unroll
    for (int t = 0; t < 4; ++t) {
        int mp = mb + t * 16 + li;                     // m' = c*384 + a
        int a = mp % NA, c = mp / NA;
        const float* src = w2 + ((size_t)a * NC + c) * NH + quad * 8;
        float4 v0 = *(const float4*)(src);
        float4 v1 = *(const float4*)(src + 4);
        uint16_t tmp[8] = { f2bf(v0.x), f2bf(v0.y), f2bf(v0.z), f2bf(v0.w),
                            f2bf(v1.x), f2bf(v1.y), f2bf(v1.z), f2bf(v1.w) };
        __builtin_memcpy(&afrag[t], tmp, 16);
        float bv[4];
#pragma unroll
        for (int r = 0; r < 4; ++r) {
            int mpr = mb + t * 16 + quad * 4 + r;
            bv[r] = b2[(size_t)(mpr % NA) * NC + (mpr / NA)];
        }
        bias[t] = make_float4(bv[0], bv[1], bv[2], bv[3]);
    }

    for (int g = 0; g < 10; ++g) {
        int cl0 = blockIdx.y * 160 + g * 16;           // local chunk base
        if (cl0 >= nchunk) break;
        int cl = cl0 + li;
        if (cl >= nchunk) cl = nchunk - 1;
        bf16x8 hfrag = *(const bf16x8*)(Hb + (size_t)(chunk0 + cl) * NH + quad * 8);
#pragma unroll
        for (int t = 0; t < 4; ++t) {
            f32x4 acc = {0.f, 0.f, 0.f, 0.f};
            acc = __builtin_amdgcn_mfma_f32_16x16x32_bf16(afrag[t], hfrag, acc, 0, 0, 0);
            uint16_t p[4] = { f2bf(acc[0] + bias[t].x), f2bf(acc[1] + bias[t].y),
                              f2bf(acc[2] + bias[t].z), f2bf(acc[3] + bias[t].w) };
            uint64_t pv; __builtin_memcpy(&pv, p, 8);
            *(uint64_t*)&St[w][li][t * 16 + quad * 4] = pv;
        }
        // same-wave readback (compiler inserts lgkmcnt wait) + coalesced store
#pragma unroll
        for (int p = 0; p < 2; ++p) {
            int ch = (lane >> 3) + p * 8, part = lane & 7;
            uint4 v = *(const uint4*)&St[w][ch][part * 8];
            int cg = cl0 + ch;
            if (cg < nchunk)
                *(uint4*)(Wt + (size_t)cg * MW + mb + part * 8) = v;
        }
    }
}

// ---------------------------------------------------------------------------
// k3: per-chunk conv GEMM, v6 — x-transpose fused into the prologue.
// k0x and the Xt intermediate are DELETED (-27 µs dispatch, -98 MB traffic):
// each block reads its own x window [128 cin][~124 t] f32 (512 B contiguous
// runs), converts to bf16 in registers, and writes the IDENTICAL swizzled
// Xa layout via packed ds_write_b32 (cin-pair per lane). Rows 0,1 = causal
// pad / previous-chunk tail via aligned float2 loads; rows >=122 garbage-
// but-discarded (reads use r <= 121). D0/D1 W-stages issue FIRST so their
// latency hides under the transpose arithmetic. MFMA loop, tri-buffer W
// pipeline (counted vmcnt), epilogue unchanged -> Xa bit-identical.
// ---------------------------------------------------------------------------
__global__ __launch_bounds__(512, 4) void k3_conv(
    const float* __restrict__ x, const uint16_t* __restrict__ Wt,
    const float* __restrict__ biasws, float* __restrict__ out, int chunk0) {
    int cl = blockIdx.x, chunk = chunk0 + cl;
    int b = chunk / NK, k = chunk - b * NK;
    int kbase = k * TK;
    int tid = threadIdx.x, lane = tid & 63, w = tid >> 6;   // w 0..7
    int quad = lane >> 4, li = lane & 15;
    int tblk = (w >> 1) * 32, cblk = (w & 1) * 64;

    __shared__ __align__(16) char smem[81920];
    char* Xa  = smem;             // 128 rows x 256B (cin-unit XOR-swizzled)
    char* Db0 = smem + 32768;     // W tri-buf: [c 128][8 slot^(c&7)][8a] =16KB
    char* Db1 = smem + 49152;
    char* Db2 = smem + 65536;
    const uint16_t* WtC = Wt + (size_t)cl * MW;

    // stage of W for one dk: 16 insts/block (2/wave), each 8x128B source runs
    auto stageD = [&](char* dst, int dks) {
#pragma unroll
        for (int j = 0; j < 2; ++j) {
            int g = (w * 2 + j) * 64 + lane;          // 16B-unit index 0..1023
            int c = g >> 3, sd = g & 7;               // 8 units per c
            int o = sd ^ (c & 7);                     // inverse slot swizzle
            const uint16_t* gsrc = WtC + (size_t)c * NA + dks * 64 + o * 8;
            __builtin_amdgcn_global_load_lds(
                (__attribute__((address_space(1))) void*)gsrc,
                (__attribute__((address_space(3))) void*)(dst + (w * 2 + j) * 1024),
                16, 0, 0);
        }
    };

    // issue W stages first: latency hides under the transpose below
    stageD(Db0, 0);
    stageD(Db1, 1);

    // ---- A-transpose staging: x f32 -> Xa bf16, swizzled (replaces Xt)
    const float* xb = x + (size_t)b * NC * TT;
    {
        int thalf = lane >> 5;            // 0..1
        int tq4 = (lane & 31) * 4;        // 0..124
#pragma unroll
        for (int i = 0; i < 4; ++i) {
            int p = i * 16 + w * 2 + thalf;   // cin-pair index 0..63
            int cin = p * 2;
            int tg = kbase + tq4;             // 16B-aligned t base
            int tga = tg > TT - 4 ? TT - 4 : tg;   // clamp: rows >=122 only
            float4 v0 = *(const float4*)(xb + (size_t)cin * TT + tga);
            float4 v1 = *(const float4*)(xb + (size_t)(cin + 1) * TT + tga);
            uint32_t pks[4] = { pk2u(f2bf(v0.x), f2bf(v1.x)),
                                pk2u(f2bf(v0.y), f2bf(v1.y)),
                                pk2u(f2bf(v0.z), f2bf(v1.z)),
                                pk2u(f2bf(v0.w), f2bf(v1.w)) };
            int q = cin >> 3, wi = (cin & 7) * 2;
#pragma unroll
            for (int j = 0; j < 4; ++j) {
                int r = tq4 + 2 + j;          // row r holds x[kbase + r - 2]
                if (r < 128)
                    *(uint32_t*)(Xa + r * 256 + ((q ^ (r & 15)) << 4) + wi) = pks[j];
            }
            if (tq4 == 0) {   // rows 0,1: previous-chunk tail or causal zeros
                uint32_t r0 = 0, r1 = 0;
                if (kbase > 0) {
                    float2 u0 = *(const float2*)(xb + (size_t)cin * TT + kbase - 2);
                    float2 u1 = *(const float2*)(xb + (size_t)(cin + 1) * TT + kbase - 2);
                    r0 = pk2u(f2bf(u0.x), f2bf(u1.x));
                    r1 = pk2u(f2bf(u0.y), f2bf(u1.y));
                }
                *(uint32_t*)(Xa + (q << 4) + wi) = r0;
                *(uint32_t*)(Xa + 256 + ((q ^ 1) << 4) + wi) = r1;
            }
        }
    }
    asm volatile("s_waitcnt lgkmcnt(0)" ::: "memory");   // publish Xa (own wave)

    f32x4 acc[2][4];
#pragma unroll
    for (int i = 0; i < 2; ++i)
#pragma unroll
        for (int j = 0; j < 4; ++j) acc[i][j] = (f32x4){0.f, 0.f, 0.f, 0.f};

#pragma unroll
    for (int dk = 0; dk < 6; ++dk) {
        // wait own D(dk) loads (leave D(dk+1)'s 2 in flight), then barrier:
        // all waves' D(dk) writes + Xa ds_writes visible.
        if (dk < 5) asm volatile("s_waitcnt vmcnt(2)" ::: "memory");
        else        asm volatile("s_waitcnt vmcnt(0)" ::: "memory");
        __builtin_amdgcn_s_barrier();
        __builtin_amdgcn_sched_barrier(0);
        if (dk < 4) {   // issue D(dk+2) into the buffer read at dk-1
            int sel = (dk + 2) % 3;
            stageD(sel == 0 ? Db0 : (sel == 1 ? Db1 : Db2), dk + 2);
        }
        int cs = dk % 3;
        char* cur = cs == 0 ? Db0 : (cs == 1 ? Db1 : Db2);
        int tap = dk >> 1;

        bf16x8 bfr[2][4];
#pragma unroll
        for (int s = 0; s < 2; ++s)
#pragma unroll
            for (int ct = 0; ct < 4; ++ct) {
                int c = cblk + ct * 16 + li;
                bfr[s][ct] = *(const bf16x8*)(cur + c * 128
                             + (((s * 4 + quad) ^ (c & 7)) << 4));
            }
#pragma unroll
        for (int s = 0; s < 2; ++s) {
            bf16x8 af[2];
#pragma unroll
            for (int tt = 0; tt < 2; ++tt) {
                int r = tblk + tt * 16 + li + 2 - tap;
                r = r > 127 ? 127 : r;     // clamped rows feed only discarded t
                int q = (dk & 1) * 8 + s * 4 + quad;
                af[tt] = *(const bf16x8*)(Xa + r * 256 + ((q ^ (r & 15)) << 4));
            }
#pragma unroll
            for (int tt = 0; tt < 2; ++tt)
#pragma unroll
                for (int ct = 0; ct < 4; ++ct)
                    acc[tt][ct] = __builtin_amdgcn_mfma_f32_16x16x32_bf16(
                        af[tt], bfr[s][ct], acc[tt][ct], 0, 0, 0);
        }
    }

    // epilogue: D col = c = lane&15 (+tile), row = t = quad*4+reg (+tile)
#pragma unroll
    for (int ct = 0; ct < 4; ++ct) {
        int c = cblk + ct * 16 + li;
        float bias = biasws[(size_t)chunk * NC + c];
        float* ob = out + ((size_t)b * NC + c) * TT + kbase;
#pragma unroll
        for (int tt = 0; tt < 2; ++tt) {
            int t0v = tblk + tt * 16 + quad * 4;
            if (t0v < TK) {
                f32x4 v = acc[tt][ct];
                *(float4*)(ob + t0v) = make_float4(v[0] + bias, v[1] + bias,
                                                   v[2] + bias, v[3] + bias);
            }
        }
    }
}

// ---------------------------------------------------------------------------
// launch
// ---------------------------------------------------------------------------
extern "C" void kernel_launch(void* const* d_in, const int* in_sizes, int n_in,
                              void* d_out, int out_size, void* d_ws, size_t ws_size,
                              hipStream_t stream) {
    const float* x   = (const float*)d_in[0];
    const float* z   = (const float*)d_in[1];
    const float* w1  = (const float*)d_in[2];
    const float* b1  = (const float*)d_in[3];
    const float* w2  = (const float*)d_in[4];
    const float* b2  = (const float*)d_in[5];
    const float* bw1 = (const float*)d_in[6];
    const float* bb1 = (const float*)d_in[7];
    const float* bw2 = (const float*)d_in[8];
    const float* bb2 = (const float*)d_in[9];
    float* out = (float*)d_out;

    // ws layout (all 256-aligned); Xt is GONE (transpose fused into k3):
    char* ws = (char*)d_ws;
    uint16_t* Hb     = (uint16_t*)(ws);                 //   102,400 B
    float*    biasws = (float*)(ws + 102400);           //   819,200 B
    const size_t wt_off = 921600;
    uint16_t* Wt     = (uint16_t*)(ws + wt_off);        // slice buffer

    // L3 blocking: 800 chunks -> 78.6 MB Wt slice; 78 Wt + 98 out + 98 x
    // working set cycles through 256 MB L3.
    size_t avail = (ws_size > wt_off) ? (ws_size - wt_off) : 0;
    int batch = (int)(avail / ((size_t)MW * 2));
    if (batch > 800) batch = 800;
    if (batch < 1) batch = 1;

    k1_hidden<<<NCHUNK / 4, 256, 0, stream>>>(z, w1, b1, bw1, bb1, bw2, bb2, Hb, biasws);

    for (int c0 = 0; c0 < NCHUNK; c0 += batch) {
        int nc = NCHUNK - c0;
        if (nc > batch) nc = batch;
        dim3 g2(MW / 256, (nc + 159) / 160, 1);
        k2_wgen<<<g2, 256, 0, stream>>>(w2, b2, Hb, Wt, c0, nc);
        k3_conv<<<nc, 512, 0, stream>>>(x, Wt, biasws, out, c0);
    }
}